// Round 8
// baseline (289.220 us; speedup 1.0000x reference)
//
#include <hip/hip_runtime.h>
#include <hip/hip_bf16.h>

// MultiScaleAttentionPE — MI355X round 11
// FULL AFFINE COLLAPSE: every level pe_L is a rank-{2,4,6,8,9} affine function
// of gathered xyz triples. pe0[i] = e0 + sum_t x[g_t(i)] @ E_t with the chain
// j=idx0[i], k=k12[j], l=k23[k], m=k34[l]. All GEMMs fold into precomputed
// 3x256 matrix chains (fp32). No MFMA, no P^T, no intermediate pe buffers,
// no inter-level data dependency: ONE output kernel computes all 5 levels.
// Launches: prep+nn -> chain S3..S0 (4 tiny) -> out. 6 total.

typedef __hip_bfloat16 bf16;
typedef unsigned short ushort_t;

#define cN0 65536
#define cN1 16384
#define cN2 4096
#define cN3 1024
#define cN4 256

__device__ __forceinline__ float bits2f(ushort_t u) {
    union { unsigned u; float f; } x; x.u = ((unsigned)u) << 16; return x.f;
}
__device__ __forceinline__ float ldf(const void* raw, int fp32, int i) {
    return fp32 ? ((const float*)raw)[i] : bits2f(((const ushort_t*)raw)[i]);
}
__device__ __forceinline__ float3 ld3(const void* raw, int fp32, int i) {
    if (fp32) {
        const float* f = (const float*)raw + 3 * i;
        return make_float3(f[0], f[1], f[2]);
    }
    const ushort_t* u = (const ushort_t*)raw + 3 * i;
    return make_float3(bits2f(u[0]), bits2f(u[1]), bits2f(u[2]));
}

struct RawArgs {
    const void* xyz;
    const void* Wall; const void* ball;
    const void* W[5]; const void* bb[5];
    const void* P[5]; const void* pb[5];
};

// ---------------- launch 1: prep (G/H/d + L4 bundle) + nn ----------------
// blocks  0..39 : G=W@Ptop, H=Wall@Pbot, d=b@Ptop+ball@Pbot+pb per level
//                 (L=b>>3 maps to levels 4..0; L==0 inlines cls4 into e4 and
//                  writes the level-4 bundle MATS0 = [G4;H4;e4])
// blocks 40..375: 1-NN argmin (16 blk k34, 64 blk k23, 256 blk k12)

__device__ __forceinline__ void nn_body(const void* xyzr, int fp32,
                                        const int* __restrict__ idxQ,
                                        const int* __restrict__ idxR, int nR,
                                        int* __restrict__ outK, int blk,
                                        float4* ref4, float* redD, int* redI) {
    int tid = threadIdx.x;
    int part = tid >> 6;                   // 0..7
    int q = blk * 64 + (tid & 63);
    int qi = idxQ[q];
    float3 qv = ld3(xyzr, fp32, qi);
    float qx = qv.x, qy = qv.y, qz = qv.z;
    float q2 = (qx * qx + qy * qy) + qz * qz;
    float best = 3.402823466e38f;
    int bi = 0;
    for (int base = 0; base < nR; base += 1024) {
        int nt = min(1024, nR - base);
        __syncthreads();
        for (int t = tid; t < nt; t += 512) {
            int ri = idxR[base + t];
            float3 r3 = ld3(xyzr, fp32, ri);
            ref4[t] = make_float4(r3.x, r3.y, r3.z,
                                  (r3.x * r3.x + r3.y * r3.y) + r3.z * r3.z);
        }
        __syncthreads();
        int seg = nt >> 3;
        int s0 = part * seg;
        for (int t = 0; t < seg; ++t) {
            float4 rp = ref4[s0 + t];
            float dot = (qx * rp.x + qy * rp.y) + qz * rp.z;
            float d = (q2 - 2.0f * dot) + rp.w;
            if (d < best) { best = d; bi = base + s0 + t; }
        }
    }
    redD[tid] = best;
    redI[tid] = bi;
    __syncthreads();
    if (part == 0) {
#pragma unroll
        for (int p = 1; p < 8; ++p) {
            float d = redD[tid + p * 64];
            int i2 = redI[tid + p * 64];
            if (d < best || (d == best && i2 < bi)) { best = d; bi = i2; }
        }
        outK[q] = bi;
    }
}

__global__ void prep_nn_kernel(RawArgs ra,
                               const int* __restrict__ idx1, const int* __restrict__ idx2,
                               const int* __restrict__ idx3, const int* __restrict__ idx4,
                               float* __restrict__ M1, float* __restrict__ M2,
                               float* __restrict__ cbuf,
                               float* __restrict__ MATS0,
                               int* __restrict__ k34, int* __restrict__ k23,
                               int* __restrict__ k12,
                               int* __restrict__ flag) {
    __shared__ __align__(16) char smem[20608];
    __shared__ int sbad;
    int b = blockIdx.x;
    int tid = threadIdx.x;

    // inline dtype detect (identical arithmetic to original detect)
    if (tid == 0) sbad = 0;
    __syncthreads();
    {
        const ushort_t* raw0 = (const ushort_t*)ra.xyz;
        for (int i = tid; i < 1024; i += 512) {
            int e = (raw0[i] >> 7) & 0xFF;
            if (e >= 138) atomicOr(&sbad, 1);
        }
    }
    __syncthreads();
    int fp32 = sbad ? 1 : 0;
    if (b == 0 && tid == 0) flag[0] = fp32;

    if (b < 40) {
        // ---- consts path ----
        int L = b >> 3;                 // 0 => level4 ... 4 => level0
        int tb = b & 7;
        const void* P = ra.P[L];
        const void* W = ra.W[L];
        const void* bvec = ra.bb[L];
        const void* pb = ra.pb[L];
        float* cls4f = (float*)smem;                 // 256
        float* red = (float*)(smem + 1024);          // 7*256
        float* px = (float*)(smem + 1024 + 7168);
        float* py = px + 256;
        float* pz = py + 256;

        if (L == 0) {
            if (tid < 256) {
                float3 x = ld3(ra.xyz, fp32, tid);
                px[tid] = x.x; py[tid] = x.y; pz[tid] = x.z;
            }
            __syncthreads();
            if (tid < 256) {
                float w0 = ldf(ra.Wall, fp32, tid);
                float w1 = ldf(ra.Wall, fp32, 256 + tid);
                float w2 = ldf(ra.Wall, fp32, 512 + tid);
                float bbv = ldf(ra.ball, fp32, tid);
                float best = -3.402823466e38f;
                for (int i = 0; i < 256; ++i) {
                    float v = fmaf(pz[i], w2, fmaf(py[i], w1, px[i] * w0)) + bbv;
                    best = fmaxf(best, v);
                }
                cls4f[tid] = best;
            }
            __syncthreads();
        }

        if (tid < 256) {
            int j = tid & 31;
            int slice = tid >> 5;
            int col = tb * 32 + j;
            float m10 = 0.f, m11 = 0.f, m12 = 0.f, m20 = 0.f, m21 = 0.f, m22 = 0.f, cc = 0.f;
#pragma unroll 4
            for (int i = 0; i < 32; ++i) {
                int c = slice * 32 + i;
                float pt = ldf(P, fp32, c * 256 + col);
                float pbot = ldf(P, fp32, (256 + c) * 256 + col);
                m10 = fmaf(ldf(W, fp32, c), pt, m10);
                m11 = fmaf(ldf(W, fp32, 256 + c), pt, m11);
                m12 = fmaf(ldf(W, fp32, 512 + c), pt, m12);
                m20 = fmaf(ldf(ra.Wall, fp32, c), pbot, m20);
                m21 = fmaf(ldf(ra.Wall, fp32, 256 + c), pbot, m21);
                m22 = fmaf(ldf(ra.Wall, fp32, 512 + c), pbot, m22);
                cc = fmaf(ldf(bvec, fp32, c), pt, cc);
                cc = fmaf(ldf(ra.ball, fp32, c), pbot, cc);
                if (L == 0) cc = fmaf(cls4f[c], pt, cc);
            }
            red[0 * 256 + tid] = m10; red[1 * 256 + tid] = m11; red[2 * 256 + tid] = m12;
            red[3 * 256 + tid] = m20; red[4 * 256 + tid] = m21; red[5 * 256 + tid] = m22;
            red[6 * 256 + tid] = cc;
        }
        __syncthreads();
        if (tid < 32) {
            int col = tb * 32 + tid;
            float v[7];
#pragma unroll
            for (int q = 0; q < 7; ++q) {
                float s = red[q * 256 + tid];
#pragma unroll
                for (int sl = 1; sl < 8; ++sl) s += red[q * 256 + sl * 32 + tid];
                v[q] = s;
            }
            M1[(size_t)L * 768 + col] = v[0];
            M1[(size_t)L * 768 + 256 + col] = v[1];
            M1[(size_t)L * 768 + 512 + col] = v[2];
            M2[(size_t)L * 768 + col] = v[3];
            M2[(size_t)L * 768 + 256 + col] = v[4];
            M2[(size_t)L * 768 + 512 + col] = v[5];
            float e = v[6] + ldf(pb, fp32, col);
            cbuf[(size_t)L * 256 + col] = e;
            if (L == 0) {
                // level-4 bundle: [G4(3 rows); H4(3 rows); e4]
                MATS0[0 * 256 + col] = v[0];
                MATS0[1 * 256 + col] = v[1];
                MATS0[2 * 256 + col] = v[2];
                MATS0[3 * 256 + col] = v[3];
                MATS0[4 * 256 + col] = v[4];
                MATS0[5 * 256 + col] = v[5];
                MATS0[6 * 256 + col] = e;
            }
        }
        return;
    }

    // ---- nn path ----
    int blk = b - 40;
    float4* ref4 = (float4*)smem;              // 1024 * 16B
    float* redD = (float*)(smem + 16384);      // 512
    int* redI = (int*)(smem + 18432);          // 512
    if (blk < 16)       nn_body(ra.xyz, fp32, idx3, idx4, cN4, k34, blk, ref4, redD, redI);
    else if (blk < 80)  nn_body(ra.xyz, fp32, idx2, idx3, cN3, k23, blk - 16, ref4, redD, redI);
    else                nn_body(ra.xyz, fp32, idx1, idx2, cN2, k12, blk - 80, ref4, redD, redI);
}

// ---------------- chain stage: out bundle = [in_mats @ Ptop (with -G at subG);
//                  appended G,H (or G+H); e_out = e_in @ Ptop + d] ----------------
// grid = n_out rows; 256 threads = one output column each.
__global__ void chain_kernel(const float* __restrict__ inB, int nin_m, int subG0,
                             const void* __restrict__ Praw,
                             const float* __restrict__ G, const float* __restrict__ H,
                             const float* __restrict__ dvec,
                             float* __restrict__ outB, int addMode,
                             const int* __restrict__ flag) {
    __shared__ float srow[256];
    int b = blockIdx.x, col = threadIdx.x;
    int nout = gridDim.x;
    int fp32 = flag[0];

    if (b < nin_m || b == nout - 1) {
        int r = (b == nout - 1) ? nin_m : b;
        srow[col] = inB[r * 256 + col];
        __syncthreads();
        float acc = 0.f;
        for (int c = 0; c < 256; c += 4) {
            float p0 = ldf(Praw, fp32, (c + 0) * 256 + col);
            float p1 = ldf(Praw, fp32, (c + 1) * 256 + col);
            float p2 = ldf(Praw, fp32, (c + 2) * 256 + col);
            float p3 = ldf(Praw, fp32, (c + 3) * 256 + col);
            acc = fmaf(srow[c + 0], p0, acc);
            acc = fmaf(srow[c + 1], p1, acc);
            acc = fmaf(srow[c + 2], p2, acc);
            acc = fmaf(srow[c + 3], p3, acc);
        }
        if (b == nout - 1) acc += dvec[col];
        else if (b >= subG0 && b < subG0 + 3) acc -= G[(b - subG0) * 256 + col];
        outB[b * 256 + col] = acc;
    } else {
        int rr = b - nin_m;
        float v;
        if (addMode) v = G[rr * 256 + col] + H[rr * 256 + col];
        else         v = (rr < 3) ? G[rr * 256 + col] : H[(rr - 3) * 256 + col];
        outB[b * 256 + col] = v;
    }
}

// ---------------- output kernel: all levels, rank-NT affine ----------------
template<int NT>
__device__ __forceinline__ void out_body(
    int row0, size_t off, const float* __restrict__ MB,
    const void* __restrict__ xyz, int fp32,
    const int* __restrict__ idx0, const int* __restrict__ idx1,
    const int* __restrict__ idx2, const int* __restrict__ idx3,
    const int* __restrict__ idx4,
    const int* __restrict__ k34, const int* __restrict__ k23,
    const int* __restrict__ k12,
    void* __restrict__ outv, float (*trips)[28]) {
    int tid = threadIdx.x;
    if (tid < 32) {
        int row = row0 + tid;
        int t[NT];
        if constexpr (NT == 9) {
            int j = idx0[row], k = k12[j], l = k23[k], m = k34[l];
            t[0] = idx4[m]; t[1] = m; t[2] = idx3[l]; t[3] = l;
            t[4] = idx2[k]; t[5] = k; t[6] = idx1[j]; t[7] = j; t[8] = row;
        } else if constexpr (NT == 8) {
            int k = k12[row], l = k23[k], m = k34[l];
            t[0] = idx4[m]; t[1] = m; t[2] = idx3[l]; t[3] = l;
            t[4] = idx2[k]; t[5] = k; t[6] = idx1[row]; t[7] = row;
        } else if constexpr (NT == 6) {
            int l = k23[row], m = k34[l];
            t[0] = idx4[m]; t[1] = m; t[2] = idx3[l]; t[3] = l;
            t[4] = idx2[row]; t[5] = row;
        } else if constexpr (NT == 4) {
            int m = k34[row];
            t[0] = idx4[m]; t[1] = m; t[2] = idx3[row]; t[3] = row;
        } else {
            t[0] = idx4[row]; t[1] = row;
        }
#pragma unroll
        for (int q = 0; q < NT; ++q) {
            float3 x = ld3(xyz, fp32, t[q]);
            trips[tid][3 * q + 0] = x.x;
            trips[tid][3 * q + 1] = x.y;
            trips[tid][3 * q + 2] = x.z;
        }
    }
    int col = tid;
    float M[3 * NT];
#pragma unroll
    for (int r = 0; r < 3 * NT; ++r) M[r] = MB[r * 256 + col];
    float ev = MB[3 * NT * 256 + col];
    __syncthreads();
#pragma unroll 4
    for (int rr = 0; rr < 32; ++rr) {
        float v = ev;
#pragma unroll
        for (int q = 0; q < NT; ++q) {
            v = fmaf(trips[rr][3 * q + 0], M[3 * q + 0], v);
            v = fmaf(trips[rr][3 * q + 1], M[3 * q + 1], v);
            v = fmaf(trips[rr][3 * q + 2], M[3 * q + 2], v);
        }
        size_t idx = off + (size_t)(row0 + rr) * 256 + col;
        if (fp32) ((float*)outv)[idx] = v;
        else      ((bf16*)outv)[idx] = __float2bfloat16(v);
    }
}

__global__ __launch_bounds__(256) void out_kernel(
    const void* __restrict__ xyz,
    const int* __restrict__ idx0, const int* __restrict__ idx1,
    const int* __restrict__ idx2, const int* __restrict__ idx3,
    const int* __restrict__ idx4,
    const int* __restrict__ k34, const int* __restrict__ k23,
    const int* __restrict__ k12,
    const float* __restrict__ MATS,
    const int* __restrict__ flag, void* __restrict__ outv) {
    __shared__ float trips[32][28];
    int b = blockIdx.x;
    int fp32 = flag[0];
    const size_t o4 = 0, o3 = 65536, o2 = 327680, o1 = 1376256, o0 = 5570560;
    if (b < 2048)
        out_body<9>(b * 32, o0, MATS + 4 * 7168, xyz, fp32,
                    idx0, idx1, idx2, idx3, idx4, k34, k23, k12, outv, trips);
    else if (b < 2560)
        out_body<8>((b - 2048) * 32, o1, MATS + 3 * 7168, xyz, fp32,
                    idx0, idx1, idx2, idx3, idx4, k34, k23, k12, outv, trips);
    else if (b < 2688)
        out_body<6>((b - 2560) * 32, o2, MATS + 2 * 7168, xyz, fp32,
                    idx0, idx1, idx2, idx3, idx4, k34, k23, k12, outv, trips);
    else if (b < 2720)
        out_body<4>((b - 2688) * 32, o3, MATS + 1 * 7168, xyz, fp32,
                    idx0, idx1, idx2, idx3, idx4, k34, k23, k12, outv, trips);
    else
        out_body<2>((b - 2720) * 32, o4, MATS + 0 * 7168, xyz, fp32,
                    idx0, idx1, idx2, idx3, idx4, k34, k23, k12, outv, trips);
}

extern "C" void kernel_launch(void* const* d_in, const int* in_sizes, int n_in,
                              void* d_out, int out_size, void* d_ws, size_t ws_size,
                              hipStream_t stream) {
    const int* idx0 = (const int*)d_in[1];
    const int* idx1 = (const int*)d_in[2];
    const int* idx2 = (const int*)d_in[3];
    const int* idx3 = (const int*)d_in[4];
    const int* idx4 = (const int*)d_in[5];

    float* ws = (float*)d_ws;
    int* flag = (int*)ws;            // ws[0..63] reserved
    float* p = ws + 64;
    float* M1buf = p; p += 5 * 768;
    float* M2buf = p; p += 5 * 768;
    float* cbuf = p;  p += 5 * 256;
    int* k34 = (int*)p; p += 1024;
    int* k23 = (int*)p; p += 4096;
    int* k12 = (int*)p; p += 16384;
    float* MATS = p;  p += 5 * 7168;   // 5 bundles, up to 28 rows x 256 each

    RawArgs ra;
    ra.xyz = d_in[0];
    ra.Wall = d_in[6];
    ra.ball = d_in[7];
    for (int i = 0; i < 5; ++i) {
        ra.W[i] = d_in[8 + 2 * i];      // W4..W0
        ra.bb[i] = d_in[9 + 2 * i];
        ra.P[i] = d_in[18 + 2 * i];     // P4..P0
        ra.pb[i] = d_in[19 + 2 * i];
    }

    prep_nn_kernel<<<376, 512, 0, stream>>>(ra, idx1, idx2, idx3, idx4,
                                            M1buf, M2buf, cbuf, MATS,
                                            k34, k23, k12, flag);

    // chain: level 3 (13 rows), 2 (19), 1 (25), 0 (28)
    chain_kernel<<<13, 256, 0, stream>>>(MATS + 0 * 7168, 6, 0, ra.P[1],
                                         M1buf + 1 * 768, M2buf + 1 * 768,
                                         cbuf + 1 * 256, MATS + 1 * 7168, 0, flag);
    chain_kernel<<<19, 256, 0, stream>>>(MATS + 1 * 7168, 12, 6, ra.P[2],
                                         M1buf + 2 * 768, M2buf + 2 * 768,
                                         cbuf + 2 * 256, MATS + 2 * 7168, 0, flag);
    chain_kernel<<<25, 256, 0, stream>>>(MATS + 2 * 7168, 18, 12, ra.P[3],
                                         M1buf + 3 * 768, M2buf + 3 * 768,
                                         cbuf + 3 * 256, MATS + 3 * 7168, 0, flag);
    chain_kernel<<<28, 256, 0, stream>>>(MATS + 3 * 7168, 24, 18, ra.P[4],
                                         M1buf + 4 * 768, M2buf + 4 * 768,
                                         cbuf + 4 * 256, MATS + 4 * 7168, 1, flag);

    out_kernel<<<2728, 256, 0, stream>>>(d_in[0], idx0, idx1, idx2, idx3, idx4,
                                         k34, k23, k12, MATS, flag, d_out);
}

// Round 9
// 258.588 us; speedup vs baseline: 1.1185x; 1.1185x over previous
//
#include <hip/hip_runtime.h>
#include <hip/hip_bf16.h>

// MultiScaleAttentionPE — MI355X round 12
// Round-11 affine collapse kept (VALIDATED: absmax 0.0078, all-fp32):
//   pe_L[i] = e_L + sum_t xyz[g_t(i)] @ E_t  (rank {2,4,6,8,9} affine)
// Round-12 fix: out_kernel was LDS-issue-bound (28 ds_read per 28 fma,
//   ~20M ds ops). Rewritten register-tiled: 8x8 acc tile/thread ->
//   8 ds (broadcast) + 2 float4 glb per 64 fma. chain_kernel: 512 thr split-c.

typedef __hip_bfloat16 bf16;
typedef unsigned short ushort_t;
typedef __attribute__((ext_vector_type(8))) unsigned short ush8;

#define cN0 65536
#define cN1 16384
#define cN2 4096
#define cN3 1024
#define cN4 256

__device__ __forceinline__ float bits2f(ushort_t u) {
    union { unsigned u; float f; } x; x.u = ((unsigned)u) << 16; return x.f;
}
__device__ __forceinline__ float ldf(const void* raw, int fp32, int i) {
    return fp32 ? ((const float*)raw)[i] : bits2f(((const ushort_t*)raw)[i]);
}
__device__ __forceinline__ float3 ld3(const void* raw, int fp32, int i) {
    if (fp32) {
        const float* f = (const float*)raw + 3 * i;
        return make_float3(f[0], f[1], f[2]);
    }
    const ushort_t* u = (const ushort_t*)raw + 3 * i;
    return make_float3(bits2f(u[0]), bits2f(u[1]), bits2f(u[2]));
}

// RNE float -> bf16 bits (values are finite; no NaN path needed)
__device__ __forceinline__ ushort_t f2b(float v) {
    union { float f; unsigned u; } x; x.f = v;
    unsigned r = x.u + 0x7FFF + ((x.u >> 16) & 1);
    return (ushort_t)(r >> 16);
}

struct RawArgs {
    const void* xyz;
    const void* Wall; const void* ball;
    const void* W[5]; const void* bb[5];
    const void* P[5]; const void* pb[5];
};

// ---------------- launch 1: prep (G/H/d + L4 bundle) + nn ----------------
__device__ __forceinline__ void nn_body(const void* xyzr, int fp32,
                                        const int* __restrict__ idxQ,
                                        const int* __restrict__ idxR, int nR,
                                        int* __restrict__ outK, int blk,
                                        float4* ref4, float* redD, int* redI) {
    int tid = threadIdx.x;
    int part = tid >> 6;                   // 0..7
    int q = blk * 64 + (tid & 63);
    int qi = idxQ[q];
    float3 qv = ld3(xyzr, fp32, qi);
    float qx = qv.x, qy = qv.y, qz = qv.z;
    float q2 = (qx * qx + qy * qy) + qz * qz;
    float best = 3.402823466e38f;
    int bi = 0;
    for (int base = 0; base < nR; base += 1024) {
        int nt = min(1024, nR - base);
        __syncthreads();
        for (int t = tid; t < nt; t += 512) {
            int ri = idxR[base + t];
            float3 r3 = ld3(xyzr, fp32, ri);
            ref4[t] = make_float4(r3.x, r3.y, r3.z,
                                  (r3.x * r3.x + r3.y * r3.y) + r3.z * r3.z);
        }
        __syncthreads();
        int seg = nt >> 3;
        int s0 = part * seg;
        for (int t = 0; t < seg; ++t) {
            float4 rp = ref4[s0 + t];
            float dot = (qx * rp.x + qy * rp.y) + qz * rp.z;
            float d = (q2 - 2.0f * dot) + rp.w;
            if (d < best) { best = d; bi = base + s0 + t; }
        }
    }
    redD[tid] = best;
    redI[tid] = bi;
    __syncthreads();
    if (part == 0) {
#pragma unroll
        for (int p = 1; p < 8; ++p) {
            float d = redD[tid + p * 64];
            int i2 = redI[tid + p * 64];
            if (d < best || (d == best && i2 < bi)) { best = d; bi = i2; }
        }
        outK[q] = bi;
    }
}

__global__ void prep_nn_kernel(RawArgs ra,
                               const int* __restrict__ idx1, const int* __restrict__ idx2,
                               const int* __restrict__ idx3, const int* __restrict__ idx4,
                               float* __restrict__ M1, float* __restrict__ M2,
                               float* __restrict__ cbuf,
                               float* __restrict__ MATS0,
                               int* __restrict__ k34, int* __restrict__ k23,
                               int* __restrict__ k12,
                               int* __restrict__ flag) {
    __shared__ __align__(16) char smem[20608];
    __shared__ int sbad;
    int b = blockIdx.x;
    int tid = threadIdx.x;

    if (tid == 0) sbad = 0;
    __syncthreads();
    {
        const ushort_t* raw0 = (const ushort_t*)ra.xyz;
        for (int i = tid; i < 1024; i += 512) {
            int e = (raw0[i] >> 7) & 0xFF;
            if (e >= 138) atomicOr(&sbad, 1);
        }
    }
    __syncthreads();
    int fp32 = sbad ? 1 : 0;
    if (b == 0 && tid == 0) flag[0] = fp32;

    if (b < 40) {
        // ---- consts path ----
        int L = b >> 3;                 // 0 => level4 ... 4 => level0
        int tb = b & 7;
        const void* P = ra.P[L];
        const void* W = ra.W[L];
        const void* bvec = ra.bb[L];
        const void* pb = ra.pb[L];
        float* cls4f = (float*)smem;                 // 256
        float* red = (float*)(smem + 1024);          // 7*256
        float* px = (float*)(smem + 1024 + 7168);
        float* py = px + 256;
        float* pz = py + 256;

        if (L == 0) {
            if (tid < 256) {
                float3 x = ld3(ra.xyz, fp32, tid);
                px[tid] = x.x; py[tid] = x.y; pz[tid] = x.z;
            }
            __syncthreads();
            if (tid < 256) {
                float w0 = ldf(ra.Wall, fp32, tid);
                float w1 = ldf(ra.Wall, fp32, 256 + tid);
                float w2 = ldf(ra.Wall, fp32, 512 + tid);
                float bbv = ldf(ra.ball, fp32, tid);
                float best = -3.402823466e38f;
                for (int i = 0; i < 256; ++i) {
                    float v = fmaf(pz[i], w2, fmaf(py[i], w1, px[i] * w0)) + bbv;
                    best = fmaxf(best, v);
                }
                cls4f[tid] = best;
            }
            __syncthreads();
        }

        if (tid < 256) {
            int j = tid & 31;
            int slice = tid >> 5;
            int col = tb * 32 + j;
            float m10 = 0.f, m11 = 0.f, m12 = 0.f, m20 = 0.f, m21 = 0.f, m22 = 0.f, cc = 0.f;
#pragma unroll 4
            for (int i = 0; i < 32; ++i) {
                int c = slice * 32 + i;
                float pt = ldf(P, fp32, c * 256 + col);
                float pbot = ldf(P, fp32, (256 + c) * 256 + col);
                m10 = fmaf(ldf(W, fp32, c), pt, m10);
                m11 = fmaf(ldf(W, fp32, 256 + c), pt, m11);
                m12 = fmaf(ldf(W, fp32, 512 + c), pt, m12);
                m20 = fmaf(ldf(ra.Wall, fp32, c), pbot, m20);
                m21 = fmaf(ldf(ra.Wall, fp32, 256 + c), pbot, m21);
                m22 = fmaf(ldf(ra.Wall, fp32, 512 + c), pbot, m22);
                cc = fmaf(ldf(bvec, fp32, c), pt, cc);
                cc = fmaf(ldf(ra.ball, fp32, c), pbot, cc);
                if (L == 0) cc = fmaf(cls4f[c], pt, cc);
            }
            red[0 * 256 + tid] = m10; red[1 * 256 + tid] = m11; red[2 * 256 + tid] = m12;
            red[3 * 256 + tid] = m20; red[4 * 256 + tid] = m21; red[5 * 256 + tid] = m22;
            red[6 * 256 + tid] = cc;
        }
        __syncthreads();
        if (tid < 32) {
            int col = tb * 32 + tid;
            float v[7];
#pragma unroll
            for (int q = 0; q < 7; ++q) {
                float s = red[q * 256 + tid];
#pragma unroll
                for (int sl = 1; sl < 8; ++sl) s += red[q * 256 + sl * 32 + tid];
                v[q] = s;
            }
            M1[(size_t)L * 768 + col] = v[0];
            M1[(size_t)L * 768 + 256 + col] = v[1];
            M1[(size_t)L * 768 + 512 + col] = v[2];
            M2[(size_t)L * 768 + col] = v[3];
            M2[(size_t)L * 768 + 256 + col] = v[4];
            M2[(size_t)L * 768 + 512 + col] = v[5];
            float e = v[6] + ldf(pb, fp32, col);
            cbuf[(size_t)L * 256 + col] = e;
            if (L == 0) {
                MATS0[0 * 256 + col] = v[0];
                MATS0[1 * 256 + col] = v[1];
                MATS0[2 * 256 + col] = v[2];
                MATS0[3 * 256 + col] = v[3];
                MATS0[4 * 256 + col] = v[4];
                MATS0[5 * 256 + col] = v[5];
                MATS0[6 * 256 + col] = e;
            }
        }
        return;
    }

    // ---- nn path ----
    int blk = b - 40;
    float4* ref4 = (float4*)smem;              // 1024 * 16B
    float* redD = (float*)(smem + 16384);      // 512
    int* redI = (int*)(smem + 18432);          // 512
    if (blk < 16)       nn_body(ra.xyz, fp32, idx3, idx4, cN4, k34, blk, ref4, redD, redI);
    else if (blk < 80)  nn_body(ra.xyz, fp32, idx2, idx3, cN3, k23, blk - 16, ref4, redD, redI);
    else                nn_body(ra.xyz, fp32, idx1, idx2, cN2, k12, blk - 80, ref4, redD, redI);
}

// ---------------- chain stage (512 thr, split-c x2) ----------------
__global__ void chain_kernel(const float* __restrict__ inB, int nin_m, int subG0,
                             const void* __restrict__ Praw,
                             const float* __restrict__ G, const float* __restrict__ H,
                             const float* __restrict__ dvec,
                             float* __restrict__ outB, int addMode,
                             const int* __restrict__ flag) {
    __shared__ float srow[256];
    __shared__ float sred[2][256];
    int b = blockIdx.x;
    int tid = threadIdx.x;
    int col = tid & 255;
    int half = tid >> 8;
    int nout = gridDim.x;
    int fp32 = flag[0];

    if (b < nin_m || b == nout - 1) {
        int r = (b == nout - 1) ? nin_m : b;
        if (tid < 256) srow[tid] = inB[r * 256 + tid];
        __syncthreads();
        float acc = 0.f;
        int c0 = half * 128;
        for (int c = c0; c < c0 + 128; c += 4) {
            float p0 = ldf(Praw, fp32, (c + 0) * 256 + col);
            float p1 = ldf(Praw, fp32, (c + 1) * 256 + col);
            float p2 = ldf(Praw, fp32, (c + 2) * 256 + col);
            float p3 = ldf(Praw, fp32, (c + 3) * 256 + col);
            acc = fmaf(srow[c + 0], p0, acc);
            acc = fmaf(srow[c + 1], p1, acc);
            acc = fmaf(srow[c + 2], p2, acc);
            acc = fmaf(srow[c + 3], p3, acc);
        }
        sred[half][col] = acc;
        __syncthreads();
        if (half == 0) {
            float a = sred[0][col] + sred[1][col];
            if (b == nout - 1) a += dvec[col];
            else if (b >= subG0 && b < subG0 + 3) a -= G[(b - subG0) * 256 + col];
            outB[b * 256 + col] = a;
        }
    } else if (tid < 256) {
        int rr = b - nin_m;
        float v;
        if (addMode) v = G[rr * 256 + col] + H[rr * 256 + col];
        else         v = (rr < 3) ? G[rr * 256 + col] : H[(rr - 3) * 256 + col];
        outB[b * 256 + col] = v;
    }
}

// ---------------- output kernel: register-tiled rank-K update ----------------
// Block: 64 rows x 256 cols, 256 threads = 8 row-tiles x 32 col-tiles.
// Thread: 8x8 acc tile. Per k-slice: 8 LDS reads (2-way broadcast, free)
// + 2 float4 M loads + 64 fmaf. Same fmaf order as round 11 (bit-identical).
template<int NT>
__device__ __forceinline__ void out_tile(
    int row0, size_t off, const float* __restrict__ MB,
    const void* __restrict__ xyz, int fp32,
    const int* __restrict__ idx0, const int* __restrict__ idx1,
    const int* __restrict__ idx2, const int* __restrict__ idx3,
    const int* __restrict__ idx4,
    const int* __restrict__ k34, const int* __restrict__ k23,
    const int* __restrict__ k12,
    void* __restrict__ outv, int* sidx, float* T) {
    int tid = threadIdx.x;
    // phase 1: index chains (one thread per row)
    if (tid < 64) {
        int row = row0 + tid;
        int t[NT];
        if constexpr (NT == 9) {
            int j = idx0[row], k = k12[j], l = k23[k], m = k34[l];
            t[0] = idx4[m]; t[1] = m; t[2] = idx3[l]; t[3] = l;
            t[4] = idx2[k]; t[5] = k; t[6] = idx1[j]; t[7] = j; t[8] = row;
        } else if constexpr (NT == 8) {
            int k = k12[row], l = k23[k], m = k34[l];
            t[0] = idx4[m]; t[1] = m; t[2] = idx3[l]; t[3] = l;
            t[4] = idx2[k]; t[5] = k; t[6] = idx1[row]; t[7] = row;
        } else if constexpr (NT == 6) {
            int l = k23[row], m = k34[l];
            t[0] = idx4[m]; t[1] = m; t[2] = idx3[l]; t[3] = l;
            t[4] = idx2[row]; t[5] = row;
        } else if constexpr (NT == 4) {
            int m = k34[row];
            t[0] = idx4[m]; t[1] = m; t[2] = idx3[row]; t[3] = row;
        } else {
            t[0] = idx4[row]; t[1] = row;
        }
#pragma unroll
        for (int q = 0; q < NT; ++q) sidx[tid * 9 + q] = t[q];
    }
    __syncthreads();
    // phase 2: gather triples into T[64][29]
    for (int lin = tid; lin < 64 * NT; lin += 256) {
        int r = lin / NT, q = lin - r * NT;
        float3 x = ld3(xyz, fp32, sidx[r * 9 + q]);
        T[r * 29 + 3 * q + 0] = x.x;
        T[r * 29 + 3 * q + 1] = x.y;
        T[r * 29 + 3 * q + 2] = x.z;
    }
    __syncthreads();
    // phase 3: compute
    int tc = tid & 31, tr = tid >> 5;
    int c8 = tc * 8;
    float4 e0 = *(const float4*)(MB + 3 * NT * 256 + c8);
    float4 e1 = *(const float4*)(MB + 3 * NT * 256 + c8 + 4);
    float acc[8][8];
#pragma unroll
    for (int i = 0; i < 8; ++i) {
        acc[i][0] = e0.x; acc[i][1] = e0.y; acc[i][2] = e0.z; acc[i][3] = e0.w;
        acc[i][4] = e1.x; acc[i][5] = e1.y; acc[i][6] = e1.z; acc[i][7] = e1.w;
    }
#pragma unroll 3
    for (int q2 = 0; q2 < 3 * NT; ++q2) {
        float4 m0 = *(const float4*)(MB + q2 * 256 + c8);
        float4 m1 = *(const float4*)(MB + q2 * 256 + c8 + 4);
        float mv0 = m0.x, mv1 = m0.y, mv2 = m0.z, mv3 = m0.w;
        float mv4 = m1.x, mv5 = m1.y, mv6 = m1.z, mv7 = m1.w;
        float tv[8];
#pragma unroll
        for (int i = 0; i < 8; ++i) tv[i] = T[(tr * 8 + i) * 29 + q2];
#pragma unroll
        for (int i = 0; i < 8; ++i) {
            acc[i][0] = fmaf(tv[i], mv0, acc[i][0]);
            acc[i][1] = fmaf(tv[i], mv1, acc[i][1]);
            acc[i][2] = fmaf(tv[i], mv2, acc[i][2]);
            acc[i][3] = fmaf(tv[i], mv3, acc[i][3]);
            acc[i][4] = fmaf(tv[i], mv4, acc[i][4]);
            acc[i][5] = fmaf(tv[i], mv5, acc[i][5]);
            acc[i][6] = fmaf(tv[i], mv6, acc[i][6]);
            acc[i][7] = fmaf(tv[i], mv7, acc[i][7]);
        }
    }
    // phase 4: store
#pragma unroll
    for (int i = 0; i < 8; ++i) {
        size_t base = off + (size_t)(row0 + tr * 8 + i) * 256 + c8;
        if (fp32) {
            *(float4*)((float*)outv + base) =
                make_float4(acc[i][0], acc[i][1], acc[i][2], acc[i][3]);
            *(float4*)((float*)outv + base + 4) =
                make_float4(acc[i][4], acc[i][5], acc[i][6], acc[i][7]);
        } else {
            ush8 pk;
#pragma unroll
            for (int j = 0; j < 8; ++j) pk[j] = f2b(acc[i][j]);
            *(ush8*)((ushort_t*)outv + base) = pk;
        }
    }
}

__global__ __launch_bounds__(256) void out_kernel(
    const void* __restrict__ xyz,
    const int* __restrict__ idx0, const int* __restrict__ idx1,
    const int* __restrict__ idx2, const int* __restrict__ idx3,
    const int* __restrict__ idx4,
    const int* __restrict__ k34, const int* __restrict__ k23,
    const int* __restrict__ k12,
    const float* __restrict__ MATS,
    const int* __restrict__ flag, void* __restrict__ outv) {
    __shared__ int sidx[64 * 9];
    __shared__ float T[64 * 29];
    int b = blockIdx.x;
    int fp32 = flag[0];
    const size_t o4 = 0, o3 = 65536, o2 = 327680, o1 = 1376256, o0 = 5570560;
    if (b < 1024)
        out_tile<9>(b * 64, o0, MATS + 4 * 7168, xyz, fp32,
                    idx0, idx1, idx2, idx3, idx4, k34, k23, k12, outv, sidx, T);
    else if (b < 1280)
        out_tile<8>((b - 1024) * 64, o1, MATS + 3 * 7168, xyz, fp32,
                    idx0, idx1, idx2, idx3, idx4, k34, k23, k12, outv, sidx, T);
    else if (b < 1344)
        out_tile<6>((b - 1280) * 64, o2, MATS + 2 * 7168, xyz, fp32,
                    idx0, idx1, idx2, idx3, idx4, k34, k23, k12, outv, sidx, T);
    else if (b < 1360)
        out_tile<4>((b - 1344) * 64, o3, MATS + 1 * 7168, xyz, fp32,
                    idx0, idx1, idx2, idx3, idx4, k34, k23, k12, outv, sidx, T);
    else
        out_tile<2>((b - 1360) * 64, o4, MATS + 0 * 7168, xyz, fp32,
                    idx0, idx1, idx2, idx3, idx4, k34, k23, k12, outv, sidx, T);
}

extern "C" void kernel_launch(void* const* d_in, const int* in_sizes, int n_in,
                              void* d_out, int out_size, void* d_ws, size_t ws_size,
                              hipStream_t stream) {
    const int* idx0 = (const int*)d_in[1];
    const int* idx1 = (const int*)d_in[2];
    const int* idx2 = (const int*)d_in[3];
    const int* idx3 = (const int*)d_in[4];
    const int* idx4 = (const int*)d_in[5];

    float* ws = (float*)d_ws;
    int* flag = (int*)ws;            // ws[0..63] reserved
    float* p = ws + 64;
    float* M1buf = p; p += 5 * 768;
    float* M2buf = p; p += 5 * 768;
    float* cbuf = p;  p += 5 * 256;
    int* k34 = (int*)p; p += 1024;
    int* k23 = (int*)p; p += 4096;
    int* k12 = (int*)p; p += 16384;
    float* MATS = p;  p += 5 * 7168;   // 5 bundles, up to 28 rows x 256 each

    RawArgs ra;
    ra.xyz = d_in[0];
    ra.Wall = d_in[6];
    ra.ball = d_in[7];
    for (int i = 0; i < 5; ++i) {
        ra.W[i] = d_in[8 + 2 * i];      // W4..W0
        ra.bb[i] = d_in[9 + 2 * i];
        ra.P[i] = d_in[18 + 2 * i];     // P4..P0
        ra.pb[i] = d_in[19 + 2 * i];
    }

    prep_nn_kernel<<<376, 512, 0, stream>>>(ra, idx1, idx2, idx3, idx4,
                                            M1buf, M2buf, cbuf, MATS,
                                            k34, k23, k12, flag);

    // chain: level 3 (13 rows), 2 (19), 1 (25), 0 (28)
    chain_kernel<<<13, 512, 0, stream>>>(MATS + 0 * 7168, 6, 0, ra.P[1],
                                         M1buf + 1 * 768, M2buf + 1 * 768,
                                         cbuf + 1 * 256, MATS + 1 * 7168, 0, flag);
    chain_kernel<<<19, 512, 0, stream>>>(MATS + 1 * 7168, 12, 6, ra.P[2],
                                         M1buf + 2 * 768, M2buf + 2 * 768,
                                         cbuf + 2 * 256, MATS + 2 * 7168, 0, flag);
    chain_kernel<<<25, 512, 0, stream>>>(MATS + 2 * 7168, 18, 12, ra.P[3],
                                         M1buf + 3 * 768, M2buf + 3 * 768,
                                         cbuf + 3 * 256, MATS + 3 * 7168, 0, flag);
    chain_kernel<<<28, 512, 0, stream>>>(MATS + 3 * 7168, 24, 18, ra.P[4],
                                         M1buf + 4 * 768, M2buf + 4 * 768,
                                         cbuf + 4 * 256, MATS + 4 * 7168, 1, flag);

    out_kernel<<<1364, 256, 0, stream>>>(d_in[0], idx0, idx1, idx2, idx3, idx4,
                                         k34, k23, k12, MATS, flag, d_out);
}